// Round 2
// baseline (79.517 us; speedup 1.0000x reference)
//
#include <hip/hip_runtime.h>
#include <math.h>

// Problem constants (reference: N=16, T=2048, D=2)
#define TT     2048
#define LOG2E  1.4426950408889634f
#define LN2    0.6931471805599453f
#define LOG2PI 1.8378770664093453f

// ---------------------------------------------------------------------------
// Kernel 1: elementwise pack (fully parallel, 128 blocks).
//   packed[j] = { x_j, y_j, z_j, E_j }
//     bt_j = t_j * LOG2E / softplus(coeff)
//     z_j  = c1*r_j + bt_j        (r_j = x_j^2 + y_j^2, c1 in log2 domain)
//     E_j  = exp2(bt_j)           (decay-kernel numerator/denominator atom)
// ---------------------------------------------------------------------------
__global__ __launch_bounds__(256) void gmsm_pack(
    const float* __restrict__ time,     // N*T
    const float* __restrict__ loc,      // N*T*2
    const float* __restrict__ coeffp,
    const float* __restrict__ lsp,
    float4* __restrict__ packed,
    int total)
{
    const int idx = blockIdx.x * 256 + threadIdx.x;
    if (idx >= total) return;
    const float sp = log1pf(expf(*coeffp));          // softplus(coeff)
    const float ss = LOG2E / sp;
    const float ls = *lsp;
    const float c1 = -0.5f * expf(-2.0f * ls) * LOG2E;

    const float t   = time[idx];
    const float2 xy = ((const float2*)loc)[idx];
    const float bt  = t * ss;
    const float r   = fmaf(xy.x, xy.x, xy.y * xy.y);
    float4 o;
    o.x = xy.x;
    o.y = xy.y;
    o.z = fmaf(r, c1, bt);
    o.w = __builtin_amdgcn_exp2f(bt);
    packed[idx] = o;
}

// ---------------------------------------------------------------------------
// Kernel 2: row-per-lane. Each block owns 64 consecutive rows (lane = row);
// 8 waves split the uniform j-stream round-robin by 64-wide chunks, so every
// packed[j] access is wave-uniform -> scalar/broadcast load (no per-lane vL1
// streaming). Inner body: 2 fma + exp2 + 2 add.
// The masked tail wave's per-lane accumulation doubles as the per-row prefix
// of E, so the 8-wave LDS reduction yields B_i exactly per row.
//   out_i = LN2*( log2(s_q) - log2(s_b) + c1*r_i ) + c0
// ---------------------------------------------------------------------------
__global__ __launch_bounds__(512) void gmsm_main(
    const float4* __restrict__ packed,
    const float* __restrict__ mu0p,
    const float* __restrict__ logstd0p,
    const float* __restrict__ lsp,
    float* __restrict__ out,
    int nrowblk)                                      // N * (TT/64)
{
    // complement swizzle: pair heavy (high base) with light (low base) blocks
    const int b    = blockIdx.x;
    const int half = nrowblk >> 1;
    const int g    = (b < half) ? (b << 1) : ((((nrowblk - 1) - b) << 1) | 1);
    const int n    = g >> 5;                          // / (TT/64)
    const int base = (g & 31) << 6;

    const int tid  = threadIdx.x;
    const int lane = tid & 63;
    const int w    = __builtin_amdgcn_readfirstlane(tid >> 6);

    const float4* __restrict__ pk = packed + (size_t)n * TT;

    const float ls   = *lsp;
    const float m2c1 = expf(-2.0f * ls) * LOG2E;      // = -2*c1 > 0
    const float4 pi  = pk[base + lane];               // this lane's row
    const float u    = m2c1 * pi.x;
    const float v    = m2c1 * pi.y;

    float s_q = 0.0f;                                 // sum exp2(q_j)
    float s_b = 0.0f;                                 // sum E_j
    const int cfull = base >> 6;                      // # full 64-wide chunks

    for (int c = w; c < cfull; c += 8) {
        const float4* cp = pk + (c << 6);
        #pragma unroll 8
        for (int jj = 0; jj < 64; ++jj) {
            const float4 f = cp[jj];                  // wave-uniform address
            s_q += __builtin_amdgcn_exp2f(fmaf(u, f.x, fmaf(v, f.y, f.z)));
            s_b += f.w;
        }
    }
    // triangular tail chunk: j = base + jj, active iff jj < lane.
    // Masked s_b accumulation = per-row prefix of E within the tail chunk.
    if (w == (cfull & 7)) {
        const float4* cp = pk + base;
        for (int jj = 0; jj < 63; ++jj) {
            const float4 f = cp[jj];
            const float e = __builtin_amdgcn_exp2f(fmaf(u, f.x, fmaf(v, f.y, f.z)));
            const bool on = jj < lane;
            s_q += on ? e   : 0.0f;
            s_b += on ? f.w : 0.0f;
        }
    }

    __shared__ float ldsq[8 * 64];
    __shared__ float ldsb[8 * 64];
    ldsq[tid] = s_q;
    ldsb[tid] = s_b;
    __syncthreads();

    if (tid < 64) {
        float q = 0.0f, bsum = 0.0f;
        #pragma unroll
        for (int k = 0; k < 8; ++k) {
            q    += ldsq[(k << 6) | tid];
            bsum += ldsb[(k << 6) | tid];
        }
        const int i = base + tid;
        float res;
        if (i == 0) {
            const float mu0 = *mu0p, l0 = *logstd0p;
            const float inv = expf(-l0);
            const float4 p0 = pk[0];
            const float tx = (p0.x - mu0) * inv;
            const float ty = (p0.y - mu0) * inv;
            res = -0.5f * (tx * tx + ty * ty + 4.0f * l0 + 2.0f * LOG2PI);
        } else {
            const float c1 = -0.5f * m2c1;            // log2-domain quadratic
            const float c0 = -(2.0f * ls + LOG2PI);
            const float4 pr = pk[i];
            const float r  = fmaf(pr.x, pr.x, pr.y * pr.y);
            res = fmaf(__builtin_amdgcn_logf(q) - __builtin_amdgcn_logf(bsum)
                       + c1 * r, LN2, c0);
        }
        out[(size_t)n * TT + i] = res;
    }
}

extern "C" void kernel_launch(void* const* d_in, const int* in_sizes, int n_in,
                              void* d_out, int out_size, void* d_ws, size_t ws_size,
                              hipStream_t stream) {
    const float* time   = (const float*)d_in[0];
    const float* loc    = (const float*)d_in[1];
    const float* mu0    = (const float*)d_in[2];
    const float* logstd = (const float*)d_in[3];
    const float* coeff  = (const float*)d_in[4];
    const float* sls    = (const float*)d_in[5];
    float* out = (float*)d_out;

    const int nrows = out_size;                 // N * T = 32768
    const int nrowblk = nrows >> 6;             // 512
    float4* packed = (float4*)d_ws;             // N*T*16 B = 512 KB scratch

    gmsm_pack<<<(nrows + 255) / 256, 256, 0, stream>>>(time, loc, coeff, sls,
                                                       packed, nrows);
    gmsm_main<<<nrowblk, 512, 0, stream>>>(packed, mu0, logstd, sls, out, nrowblk);
}

// Round 3
// 71.832 us; speedup vs baseline: 1.1070x; 1.1070x over previous
//
#include <hip/hip_runtime.h>
#include <math.h>

// Problem constants (reference: N=16, T=2048, D=2)
#define TT     2048
#define LOG2E  1.4426950408889634f
#define LN2    0.6931471805599453f
#define LOG2PI 1.8378770664093453f

// ---------------------------------------------------------------------------
// Single fused kernel. One block per 64-row group (512 blocks, 8 waves).
//
// Phase 1: block cooperatively packs its own batch-slice [0, base+64) into
//          LDS:  pkl[j] = { x_j, y_j, z_j, E_j }
//            bt_j = t_j * LOG2E / softplus(coeff)
//            z_j  = c1*r_j + bt_j     (r_j = x_j^2+y_j^2, c1 in log2 domain)
//            E_j  = exp2(bt_j)
//          (raw inputs are only 384 KB total -> L2-resident re-reads; this
//           replaces the former pack kernel + 512 KB workspace round-trip)
//
// Phase 2: lane = row, 8 waves round-robin the uniform j-stream in 64-wide
//          chunks; every pkl[j] access is wave-uniform -> LDS broadcast.
//          Inner body: ds_read + 2 fma + exp2 + 2 add.
//          Masked tail chunk doubles as the per-row prefix of E.
//   out_i = LN2*( log2(s_q) - log2(s_b) + c1*r_i ) + c0
// ---------------------------------------------------------------------------
__global__ __launch_bounds__(512) void gmsm_fused(
    const float* __restrict__ time,     // N*T
    const float* __restrict__ loc,      // N*T*2
    const float* __restrict__ mu0p,
    const float* __restrict__ logstd0p,
    const float* __restrict__ coeffp,
    const float* __restrict__ lsp,
    float* __restrict__ out,
    int nrowblk)                        // N * (TT/64) = 512
{
    __shared__ float4 pkl[TT];          // 32 KB packed slice
    __shared__ float  ldsq[512];
    __shared__ float  ldsb[512];

    // complement swizzle: pair heavy (high base) with light (low base) blocks
    const int b    = blockIdx.x;
    const int half = nrowblk >> 1;
    const int g    = (b < half) ? (b << 1) : ((((nrowblk - 1) - b) << 1) | 1);
    const int n    = g >> 5;            // / (TT/64)
    const int base = (g & 31) << 6;

    const int tid  = threadIdx.x;
    const int lane = tid & 63;
    const int w    = __builtin_amdgcn_readfirstlane(tid >> 6);

    const float sp   = log1pf(expf(*coeffp));       // softplus(coeff)
    const float ss   = LOG2E / sp;
    const float ls   = *lsp;
    const float m2c1 = expf(-2.0f * ls) * LOG2E;    // = -2*c1 > 0
    const float c1   = -0.5f * m2c1;                // log2-domain quadratic

    // ---- Phase 1: pack [0, base+64) into LDS ----
    const int J = base + 64;
    const float* tp = time + (size_t)n * TT;
    const float2* lp = (const float2*)(loc + (size_t)n * TT * 2);
    for (int e = tid; e < J; e += 512) {
        const float  t  = tp[e];
        const float2 xy = lp[e];
        const float  bt = t * ss;
        const float  r  = fmaf(xy.x, xy.x, xy.y * xy.y);
        pkl[e] = make_float4(xy.x, xy.y, fmaf(r, c1, bt),
                             __builtin_amdgcn_exp2f(bt));
    }
    __syncthreads();

    // ---- Phase 2: uniform j-stream from LDS ----
    const float4 pi = pkl[base + lane];             // this lane's row
    const float u = m2c1 * pi.x;
    const float v = m2c1 * pi.y;

    float s_q = 0.0f;                               // sum exp2(q_j)
    float s_b = 0.0f;                               // sum E_j
    const int cfull = base >> 6;                    // # full 64-wide chunks

    for (int c = w; c < cfull; c += 8) {
        const float4* cp = &pkl[c << 6];
        #pragma unroll 8
        for (int jj = 0; jj < 64; ++jj) {
            const float4 f = cp[jj];                // wave-uniform broadcast
            s_q += __builtin_amdgcn_exp2f(fmaf(u, f.x, fmaf(v, f.y, f.z)));
            s_b += f.w;
        }
    }
    // triangular tail chunk: j = base + jj, active iff jj < lane.
    if (w == (cfull & 7)) {
        const float4* cp = &pkl[base];
        for (int jj = 0; jj < 63; ++jj) {
            const float4 f = cp[jj];
            const float e = __builtin_amdgcn_exp2f(fmaf(u, f.x, fmaf(v, f.y, f.z)));
            const bool on = jj < lane;
            s_q += on ? e   : 0.0f;
            s_b += on ? f.w : 0.0f;
        }
    }

    ldsq[tid] = s_q;
    ldsb[tid] = s_b;
    __syncthreads();

    // ---- Epilogue: 8-wave combine + log ratio ----
    if (tid < 64) {
        float q = 0.0f, bs = 0.0f;
        #pragma unroll
        for (int k = 0; k < 8; ++k) {
            q  += ldsq[(k << 6) | tid];
            bs += ldsb[(k << 6) | tid];
        }
        const int i = base + tid;
        float res;
        if (i == 0) {
            const float mu0 = *mu0p, l0 = *logstd0p;
            const float inv = expf(-l0);
            const float4 p0 = pkl[0];
            const float tx = (p0.x - mu0) * inv;
            const float ty = (p0.y - mu0) * inv;
            res = -0.5f * (tx * tx + ty * ty + 4.0f * l0 + 2.0f * LOG2PI);
        } else {
            const float4 pr = pkl[i];
            const float r  = fmaf(pr.x, pr.x, pr.y * pr.y);
            res = fmaf(__builtin_amdgcn_logf(q) - __builtin_amdgcn_logf(bs)
                       + c1 * r, LN2, -(2.0f * ls + LOG2PI));
        }
        out[(size_t)n * TT + i] = res;
    }
}

extern "C" void kernel_launch(void* const* d_in, const int* in_sizes, int n_in,
                              void* d_out, int out_size, void* d_ws, size_t ws_size,
                              hipStream_t stream) {
    const float* time   = (const float*)d_in[0];
    const float* loc    = (const float*)d_in[1];
    const float* mu0    = (const float*)d_in[2];
    const float* logstd = (const float*)d_in[3];
    const float* coeff  = (const float*)d_in[4];
    const float* sls    = (const float*)d_in[5];
    float* out = (float*)d_out;

    const int nrows   = out_size;       // N * T = 32768
    const int nrowblk = nrows >> 6;     // 512

    gmsm_fused<<<nrowblk, 512, 0, stream>>>(time, loc, mu0, logstd, coeff, sls,
                                            out, nrowblk);
}